// Round 1
// 122.642 us; speedup vs baseline: 1.0135x; 1.0135x over previous
//
#include <hip/hip_runtime.h>

// GLRFast forward: out = patchs - sum_e edge_weights[e] * neighbor_e(patchs)
// Fixed problem: B=4, G=8, C=32, H=128, W=128 (fp32).
// DELTAS order: e0=(-1,0) up, e1=(0,-1) left, e2=(0,+1) right, e3=(+1,0) down.
// Replicate padding == clamped indices.
//
// R6: attack the L2/L3 locality + staging redundancy of the ~36us plateau:
//  (a) 512-thread blocks covering 16 channels (grid 512 = 32bg x 8strip x
//      2half): ew slab staged 2x instead of 4x, same 16 waves/CU
//      (2 blocks x 8 waves, LDS 2x32KB=64KB <= 160KB).
//  (b) XCD-aware block decode (xcd = blockIdx%8 round-robin heuristic):
//      the two half-blocks of one (bg,strip) AND adjacent strips of the
//      same bg land on the same XCD -> ew slab + patch halo rows are L2
//      hits instead of Infinity-Cache fills.
//  (c) ew staging loads issued BEFORE the 18-row patch burst: the
//      ds_writes wait only on the 4 oldest (ew) loads, so the patch
//      burst stays in flight across staging + __syncthreads().
// Keep R4/R5 structure otherwise: full 18-row register column per thread,
// 32KB LDS weight slab, normal (non-nt) stores.

#define GLR_HW 16384   // 128*128 floats per plane

typedef float fvec4 __attribute__((ext_vector_type(4)));

__global__ __launch_bounds__(512, 4) void glr_fwd_kernel(
    const float* __restrict__ patchs,   // [B*G*C, H, W] = 1024 planes
    const float* __restrict__ ew,       // [B*G, 4, H, W]
    float* __restrict__ out)
{
    __shared__ float4 sw[2048];  // [e:4][row i:16][w4:32] = 32 KB

    const int t  = threadIdx.x;
    const int w4 = t & 31;          // vec4 index in row
    const int ch = t >> 5;          // 0..15 channel within half-group

    // XCD-aware decode: xcd = b&7 (round-robin dispatch heuristic).
    // Per XCD: 4 bgs {xcd, xcd+8, xcd+16, xcd+24}, each with all
    // (strip, half) pairs enumerated consecutively -> ew-slab sharers and
    // strip-adjacent halo sharers are co-resident on one XCD's L2.
    const int b     = blockIdx.x;        // 0..511
    const int q     = b >> 3;            // 0..63 within XCD
    const int bg    = (b & 7) + ((q >> 4) << 3);   // 0..31
    const int rr    = q & 15;
    const int strip = rr >> 1;           // rows [16s, 16s+16)
    const int hf    = rr & 1;            // which 16-channel half

    const int r0 = strip << 4;
    const int w  = w4 << 2;

    const int plane = (bg << 5) + (hf << 4) + ch;
    const float* __restrict__ P = patchs + (size_t)plane * GLR_HW + w;
    float*       __restrict__ O = out    + (size_t)plane * GLR_HW + w;

    // ---- ew slab loads FIRST (oldest in vmcnt queue) ----
    // thread t loads ew[e=k][row r0+ch][w4] for k=0..3; contiguous across t.
    const float* __restrict__ EW =
        ew + (size_t)bg * 4 * GLR_HW + ((r0 + ch) << 7) + w;
    float4 wreg[4];
    #pragma unroll
    for (int k = 0; k < 4; ++k)
        wreg[k] = *(const float4*)(EW + k * GLR_HW);

    // ---- burst-issue the whole 18-row patch column (independent loads) ----
    float4 reg[18];
    #pragma unroll
    for (int i = 0; i < 18; ++i) {
        int r = r0 + i - 1;
        r = (r < 0) ? 0 : (r > 127 ? 127 : r);
        reg[i] = *(const float4*)(P + (r << 7));
    }

    // ---- stage weight slab: [e:4][i:16][w4:32] = 32 KB ----
    // waits only vmcnt for the 4 ew loads; patch burst stays in flight.
    #pragma unroll
    for (int k = 0; k < 4; ++k)
        sw[t + (k << 9)] = wreg[k];
    __syncthreads();

    const bool atL = (w4 == 0);
    const bool atR = (w4 == 31);

    // ---- compute 16 rows from registers ----
    #pragma unroll
    for (int i = 0; i < 16; ++i) {
        const float4 up  = reg[i];
        const float4 cur = reg[i + 1];
        const float4 dn  = reg[i + 2];

        const int si = (i << 5) + w4;
        const float4 e0 = sw[si];
        const float4 e1 = sw[512 + si];
        const float4 e2 = sw[1024 + si];
        const float4 e3 = sw[1536 + si];

        // horizontal neighbors via lane shuffle; channel boundary at the
        // half-wave seam (lanes 31/32) is fixed by the edge clamps.
        float lf = __shfl_up(cur.w, 1);
        float rg = __shfl_down(cur.x, 1);
        if (atL) lf = cur.x;
        if (atR) rg = cur.w;

        fvec4 o;
        o.x = cur.x - (up.x * e0.x + lf    * e1.x + cur.y * e2.x + dn.x * e3.x);
        o.y = cur.y - (up.y * e0.y + cur.x * e1.y + cur.z * e2.y + dn.y * e3.y);
        o.z = cur.z - (up.z * e0.z + cur.y * e1.z + cur.w * e2.z + dn.z * e3.z);
        o.w = cur.w - (up.w * e0.w + cur.z * e1.w + rg    * e2.w + dn.w * e3.w);

        *(fvec4*)(O + ((r0 + i) << 7)) = o;   // normal store (no nt)
    }
}

extern "C" void kernel_launch(void* const* d_in, const int* in_sizes, int n_in,
                              void* d_out, int out_size, void* d_ws, size_t ws_size,
                              hipStream_t stream) {
    const float* patchs = (const float*)d_in[0];  // [4,8,32,128,128]
    const float* ew     = (const float*)d_in[1];  // [4,8,4,128,128]
    // d_in[2] = node_degree, unused in forward
    float* out = (float*)d_out;

    glr_fwd_kernel<<<512, 512, 0, stream>>>(patchs, ew, out);
}

// Round 2
// 121.537 us; speedup vs baseline: 1.0227x; 1.0091x over previous
//
#include <hip/hip_runtime.h>

// GLRFast forward: out = patchs - sum_e edge_weights[e] * neighbor_e(patchs)
// Fixed problem: B=4, G=8, C=32, H=128, W=128 (fp32).
// DELTAS order: e0=(-1,0) up, e1=(0,-1) left, e2=(0,+1) right, e3=(+1,0) down.
// Replicate padding == clamped indices.
//
// R7: fix the phase serialization caused by __syncthreads().
// hipcc emits `s_waitcnt vmcnt(0) lgkmcnt(0)` before every s_barrier, so
// R6's full 18-row patch burst (issued BEFORE staging) was fully drained
// at the barrier: [all reads ~15us] -> [compute ~4us] -> [stores ~11us],
// no read/store overlap => ~35us vs the 22.7us overlapped floor.
// Fix by reordering: issue ew loads + only the FIRST 6 patch rows before
// staging; barrier drains just those 10 (they arrive together at start);
// the remaining 12 rows are issued AFTER the barrier so they stream in
// overlapped with compute, and stores overlap the read tail.
// Keep R6 otherwise: 512-thread blocks (16 channels), grid 512 =
// 32bg x 8strip x 2half, XCD-aware decode, 32KB LDS ew slab, normal stores.

#define GLR_HW 16384   // 128*128 floats per plane

typedef float fvec4 __attribute__((ext_vector_type(4)));

__global__ __launch_bounds__(512, 4) void glr_fwd_kernel(
    const float* __restrict__ patchs,   // [B*G*C, H, W] = 1024 planes
    const float* __restrict__ ew,       // [B*G, 4, H, W]
    float* __restrict__ out)
{
    __shared__ float4 sw[2048];  // [e:4][row i:16][w4:32] = 32 KB

    const int t  = threadIdx.x;
    const int w4 = t & 31;          // vec4 index in row
    const int ch = t >> 5;          // 0..15 channel within half-group

    // XCD-aware decode: xcd = b&7 (round-robin dispatch heuristic).
    const int b     = blockIdx.x;        // 0..511
    const int q     = b >> 3;            // 0..63 within XCD
    const int bg    = (b & 7) + ((q >> 4) << 3);   // 0..31
    const int rr    = q & 15;
    const int strip = rr >> 1;           // rows [16s, 16s+16)
    const int hf    = rr & 1;            // which 16-channel half

    const int r0 = strip << 4;
    const int w  = w4 << 2;

    const int plane = (bg << 5) + (hf << 4) + ch;
    const float* __restrict__ P = patchs + (size_t)plane * GLR_HW + w;
    float*       __restrict__ O = out    + (size_t)plane * GLR_HW + w;

    // ---- ew slab loads FIRST (oldest in vmcnt queue) ----
    // thread t loads ew[e=k][row r0+ch][w4] for k=0..3; contiguous across t.
    const float* __restrict__ EW =
        ew + (size_t)bg * 4 * GLR_HW + ((r0 + ch) << 7) + w;
    float4 wreg[4];
    #pragma unroll
    for (int k = 0; k < 4; ++k)
        wreg[k] = *(const float4*)(EW + k * GLR_HW);

    // ---- pre-barrier: only the first 6 patch rows (warm start) ----
    float4 reg[18];
    #pragma unroll
    for (int i = 0; i < 6; ++i) {
        int r = r0 + i - 1;
        r = (r < 0) ? 0 : (r > 127 ? 127 : r);
        reg[i] = *(const float4*)(P + (r << 7));
    }

    // ---- stage weight slab: [e:4][i:16][w4:32] = 32 KB ----
    // The barrier's implicit vmcnt(0) drains only ew + 6 rows, all of
    // which were issued together at kernel start.
    #pragma unroll
    for (int k = 0; k < 4; ++k)
        sw[t + (k << 9)] = wreg[k];
    __syncthreads();

    // ---- post-barrier: issue the remaining 12 rows; they stream in
    //      overlapped with the compute loop below ----
    #pragma unroll
    for (int i = 6; i < 18; ++i) {
        int r = r0 + i - 1;
        r = (r < 0) ? 0 : (r > 127 ? 127 : r);
        reg[i] = *(const float4*)(P + (r << 7));
    }

    const bool atL = (w4 == 0);
    const bool atR = (w4 == 31);

    // ---- compute 16 rows from registers; stores overlap the read tail ----
    #pragma unroll
    for (int i = 0; i < 16; ++i) {
        const float4 up  = reg[i];
        const float4 cur = reg[i + 1];
        const float4 dn  = reg[i + 2];

        const int si = (i << 5) + w4;
        const float4 e0 = sw[si];
        const float4 e1 = sw[512 + si];
        const float4 e2 = sw[1024 + si];
        const float4 e3 = sw[1536 + si];

        // horizontal neighbors via lane shuffle; channel boundary at the
        // half-wave seam (lanes 31/32) is fixed by the edge clamps.
        float lf = __shfl_up(cur.w, 1);
        float rg = __shfl_down(cur.x, 1);
        if (atL) lf = cur.x;
        if (atR) rg = cur.w;

        fvec4 o;
        o.x = cur.x - (up.x * e0.x + lf    * e1.x + cur.y * e2.x + dn.x * e3.x);
        o.y = cur.y - (up.y * e0.y + cur.x * e1.y + cur.z * e2.y + dn.y * e3.y);
        o.z = cur.z - (up.z * e0.z + cur.y * e1.z + cur.w * e2.z + dn.z * e3.z);
        o.w = cur.w - (up.w * e0.w + cur.z * e1.w + rg    * e2.w + dn.w * e3.w);

        *(fvec4*)(O + ((r0 + i) << 7)) = o;   // normal store (no nt)
    }
}

extern "C" void kernel_launch(void* const* d_in, const int* in_sizes, int n_in,
                              void* d_out, int out_size, void* d_ws, size_t ws_size,
                              hipStream_t stream) {
    const float* patchs = (const float*)d_in[0];  // [4,8,32,128,128]
    const float* ew     = (const float*)d_in[1];  // [4,8,4,128,128]
    // d_in[2] = node_degree, unused in forward
    float* out = (float*)d_out;

    glr_fwd_kernel<<<512, 512, 0, stream>>>(patchs, ew, out);
}